// Round 1
// baseline (400.286 us; speedup 1.0000x reference)
//
#include <hip/hip_runtime.h>

typedef unsigned short u16;
typedef short vshort8 __attribute__((ext_vector_type(8)));
typedef __bf16 vbf16x8 __attribute__((ext_vector_type(8)));
typedef float vf32x4 __attribute__((ext_vector_type(4)));

__device__ __forceinline__ u16 f2bf(float f) {
  unsigned u = __builtin_bit_cast(unsigned, f);
  u += 0x7FFFu + ((u >> 16) & 1u);
  return (u16)(u >> 16);
}

__device__ __forceinline__ vf32x4 mfma_bf16(vshort8 a, vshort8 b, vf32x4 c) {
  return __builtin_amdgcn_mfma_f32_16x16x32_bf16(
      __builtin_bit_cast(vbf16x8, a), __builtin_bit_cast(vbf16x8, b), c, 0, 0, 0);
}

__device__ __forceinline__ void gload16(const void* g, void* l) {
  __builtin_amdgcn_global_load_lds(
      (const __attribute__((address_space(1))) void*)g,
      (__attribute__((address_space(3))) void*)l, 16, 0, 0);
}

// ---------------- fp32 -> bf16 elementwise ----------------
__global__ __launch_bounds__(256) void cvtk(const float* __restrict__ in,
                                            u16* __restrict__ out, int n4) {
  int idx = blockIdx.x * 256 + threadIdx.x;
  int stride = gridDim.x * 256;
  for (int i = idx; i < n4; i += stride) {
    float4 v = ((const float4*)in)[i];
    unsigned lo = (unsigned)f2bf(v.x) | ((unsigned)f2bf(v.y) << 16);
    unsigned hi = (unsigned)f2bf(v.z) | ((unsigned)f2bf(v.w) << 16);
    uint2 o; o.x = lo; o.y = hi;
    *(uint2*)&out[(size_t)i * 4] = o;
  }
}

// ---------------- weight transpose + cvt: W[k][n] f32 -> Wt[n][k] bf16 ----------------
__global__ __launch_bounds__(256) void wtrans(const float* __restrict__ W,
                                              u16* __restrict__ Wt) {
  __shared__ u16 tile[64][72];
  int t = threadIdx.x;
  int n0 = blockIdx.x * 64, k0 = blockIdx.y * 64;
#pragma unroll
  for (int it = 0; it < 4; ++it) {
    int cid = it * 256 + t;          // 64 rows x 16 float4-chunks
    int r = cid >> 4, c4 = cid & 15;
    float4 v = *(const float4*)&W[(k0 + r) * 1024 + n0 + c4 * 4];
    u16* d = &tile[r][c4 * 4];
    d[0] = f2bf(v.x); d[1] = f2bf(v.y); d[2] = f2bf(v.z); d[3] = f2bf(v.w);
  }
  __syncthreads();
#pragma unroll
  for (int it = 0; it < 4; ++it) {
    int cid = it * 256 + t;
    int rn = cid >> 4, c4 = cid & 15;
    unsigned lo = (unsigned)tile[c4 * 4 + 0][rn] | ((unsigned)tile[c4 * 4 + 1][rn] << 16);
    unsigned hi = (unsigned)tile[c4 * 4 + 2][rn] | ((unsigned)tile[c4 * 4 + 3][rn] << 16);
    uint2 o; o.x = lo; o.y = hi;
    *(uint2*)&Wt[(n0 + rn) * 1024 + k0 + c4 * 4] = o;
  }
}

// ---------------- V transpose: V[b*2048+s][h*64+d] -> Vt[(bh*64+d)][s] (bf16) ----------------
__global__ __launch_bounds__(256) void vtrans(const u16* __restrict__ V,
                                              u16* __restrict__ Vt) {
  __shared__ u16 tile[64][72];
  int t = threadIdx.x;
  int s0 = blockIdx.x * 64;
  int bh = blockIdx.y, b = bh >> 4, h = bh & 15;
#pragma unroll
  for (int it = 0; it < 2; ++it) {
    int cid = it * 256 + t;          // 64 rows x 8 16B-chunks
    int r = cid >> 3, c8 = cid & 7;
    vshort8 v = *(const vshort8*)&V[(size_t)(b * 2048 + s0 + r) * 1024 + h * 64 + c8 * 8];
    *(vshort8*)&tile[r][c8 * 8] = v;
  }
  __syncthreads();
#pragma unroll
  for (int it = 0; it < 2; ++it) {
    int cid = it * 256 + t;
    int rd = cid >> 3, c8 = cid & 7;   // rd = d (0..63), c8 = s-chunk
    unsigned w[4];
#pragma unroll
    for (int j = 0; j < 4; ++j) {
      unsigned lo = tile[c8 * 8 + 2 * j][rd];
      unsigned hi = tile[c8 * 8 + 2 * j + 1][rd];
      w[j] = lo | (hi << 16);
    }
    uint4 o; o.x = w[0]; o.y = w[1]; o.z = w[2]; o.w = w[3];
    *(uint4*)&Vt[(size_t)(bh * 64 + rd) * 2048 + s0 + c8 * 8] = o;
  }
}

// ---------------- bf16 GEMM: C[M,N] = A[M,K] * Bt[N,K]^T ----------------
template <int OUTF32>
__global__ __launch_bounds__(256) void gemm_nt(const u16* __restrict__ A,
                                               const u16* __restrict__ Bt,
                                               float* __restrict__ Cf,
                                               u16* __restrict__ Cb,
                                               int M, int N, int K) {
  __shared__ __align__(16) u16 As[128 * 64];
  __shared__ __align__(16) u16 Bs[128 * 64];
  int t = threadIdx.x, lane = t & 63, wid = t >> 6;
  int g = lane >> 4, i16 = lane & 15;
  int n0 = blockIdx.x * 128, m0 = blockIdx.y * 128;
  int wm = wid >> 1, wn = wid & 1;

  vf32x4 acc[4][4];
#pragma unroll
  for (int a = 0; a < 4; ++a)
#pragma unroll
    for (int b = 0; b < 4; ++b) acc[a][b] = (vf32x4){0.f, 0.f, 0.f, 0.f};

  int ldsbase = (wid * 64) * 8;  // elems, per-wave chunk base
  for (int kt = 0; kt < K / 64; ++kt) {
    if (kt) __syncthreads();
#pragma unroll
    for (int it = 0; it < 4; ++it) {
      int cid = it * 256 + t;
      int row = cid >> 3, c = cid & 7, sc = c ^ (row & 7);
      gload16(A + (size_t)(m0 + row) * K + kt * 64 + sc * 8, &As[it * 2048 + ldsbase]);
    }
#pragma unroll
    for (int it = 0; it < 4; ++it) {
      int cid = it * 256 + t;
      int row = cid >> 3, c = cid & 7, sc = c ^ (row & 7);
      gload16(Bt + (size_t)(n0 + row) * K + kt * 64 + sc * 8, &Bs[it * 2048 + ldsbase]);
    }
    __syncthreads();
#pragma unroll
    for (int kc = 0; kc < 2; ++kc) {
      vshort8 af[4], bf[4];
#pragma unroll
      for (int mf = 0; mf < 4; ++mf) {
        int row = wm * 64 + mf * 16 + i16;
        int ch = (kc * 4 + g) ^ (row & 7);
        af[mf] = *(const vshort8*)&As[row * 64 + ch * 8];
      }
#pragma unroll
      for (int nf = 0; nf < 4; ++nf) {
        int row = wn * 64 + nf * 16 + i16;
        int ch = (kc * 4 + g) ^ (row & 7);
        bf[nf] = *(const vshort8*)&Bs[row * 64 + ch * 8];
      }
#pragma unroll
      for (int mf = 0; mf < 4; ++mf)
#pragma unroll
        for (int nf = 0; nf < 4; ++nf)
          acc[mf][nf] = mfma_bf16(af[mf], bf[nf], acc[mf][nf]);
    }
  }
  // epilogue
#pragma unroll
  for (int mf = 0; mf < 4; ++mf)
#pragma unroll
    for (int nf = 0; nf < 4; ++nf)
#pragma unroll
      for (int r = 0; r < 4; ++r) {
        int m = m0 + wm * 64 + mf * 16 + g * 4 + r;
        int n = n0 + wn * 64 + nf * 16 + i16;
        if (OUTF32)
          Cf[(size_t)m * N + n] = acc[mf][nf][r];
        else
          Cb[(size_t)m * N + n] = f2bf(acc[mf][nf][r]);
      }
}

// ---------------- fused flash attention ----------------
// Q,K: [8192, 1024] bf16 (row = b*2048+s, col = h*64+d)
// Vt:  [64*64, 2048] bf16 (row = bh*64+d, col = s)
// O:   [8192, 1024] bf16
__global__ __launch_bounds__(256) void attn_fwd(const u16* __restrict__ Q,
                                                const u16* __restrict__ K,
                                                const u16* __restrict__ Vt,
                                                u16* __restrict__ O) {
  __shared__ __align__(16) u16 Ks[128 * 64];      // [key][d], swizzle row&7
  __shared__ __align__(16) u16 Vs[64 * 128];      // [d][kk], swizzle row&15
  __shared__ __align__(16) u16 Ps[4 * 32 * 128];  // per-wave [q][kk], swizzle row&15

  int t = threadIdx.x, lane = t & 63, wid = t >> 6;
  int g = lane >> 4, i16 = lane & 15;
  int qb = blockIdx.x;            // 0..15
  int bh = blockIdx.y;            // 0..63
  int b = bh >> 4, h = bh & 15;
  const int ld = 1024;

  // Q fragments in registers
  vshort8 aq[2][2];
#pragma unroll
  for (int fr = 0; fr < 2; ++fr)
#pragma unroll
    for (int kc = 0; kc < 2; ++kc) {
      int grow = b * 2048 + qb * 128 + wid * 32 + fr * 16 + i16;
      aq[fr][kc] = *(const vshort8*)&Q[(size_t)grow * ld + h * 64 + kc * 32 + g * 8];
    }

  vf32x4 oacc[2][4];
  float mrow[2][4], lrow[2][4];
#pragma unroll
  for (int fr = 0; fr < 2; ++fr) {
#pragma unroll
    for (int nf = 0; nf < 4; ++nf) oacc[fr][nf] = (vf32x4){0.f, 0.f, 0.f, 0.f};
#pragma unroll
    for (int r = 0; r < 4; ++r) { mrow[fr][r] = -3.0e38f; lrow[fr][r] = 0.f; }
  }

  const u16* Kbase = K + (size_t)(b * 2048) * ld + h * 64;
  const u16* Vtbase = Vt + (size_t)(bh * 64) * 2048;
  u16* Pw = &Ps[wid * 32 * 128];
  int ldsbase = (wid * 64) * 8;

  for (int kt = 0; kt < 16; ++kt) {
    if (kt) __syncthreads();
    // stage K tile: 128 rows x 8 chunks
#pragma unroll
    for (int it = 0; it < 4; ++it) {
      int cid = it * 256 + t;
      int row = cid >> 3, c = cid & 7, sc = c ^ (row & 7);
      gload16(Kbase + (size_t)(kt * 128 + row) * ld + sc * 8, &Ks[it * 2048 + ldsbase]);
    }
    // stage Vt tile: 64 rows x 16 chunks
#pragma unroll
    for (int it = 0; it < 4; ++it) {
      int cid = it * 256 + t;
      int row = cid >> 4, c = cid & 15, sc = c ^ (row & 15);
      gload16(Vtbase + (size_t)row * 2048 + kt * 128 + sc * 8, &Vs[it * 2048 + ldsbase]);
    }
    __syncthreads();

    // S = Q K^T (scaled later)
    vf32x4 sacc[2][8];
#pragma unroll
    for (int fr = 0; fr < 2; ++fr)
#pragma unroll
      for (int fc = 0; fc < 8; ++fc) sacc[fr][fc] = (vf32x4){0.f, 0.f, 0.f, 0.f};
#pragma unroll
    for (int kc = 0; kc < 2; ++kc) {
      vshort8 bk[8];
#pragma unroll
      for (int fc = 0; fc < 8; ++fc) {
        int row = fc * 16 + i16;                 // key index in tile
        int ch = (kc * 4 + g) ^ (row & 7);
        bk[fc] = *(const vshort8*)&Ks[row * 64 + ch * 8];
      }
#pragma unroll
      for (int fr = 0; fr < 2; ++fr)
#pragma unroll
        for (int fc = 0; fc < 8; ++fc)
          sacc[fr][fc] = mfma_bf16(aq[fr][kc], bk[fc], sacc[fr][fc]);
    }

    // online softmax (scale 1/8)
#pragma unroll
    for (int fr = 0; fr < 2; ++fr) {
#pragma unroll
      for (int r = 0; r < 4; ++r) {
        float tm = sacc[fr][0][r];
#pragma unroll
        for (int fc = 1; fc < 8; ++fc) tm = fmaxf(tm, sacc[fr][fc][r]);
        tm = fmaxf(tm, __shfl_xor(tm, 1));
        tm = fmaxf(tm, __shfl_xor(tm, 2));
        tm = fmaxf(tm, __shfl_xor(tm, 4));
        tm = fmaxf(tm, __shfl_xor(tm, 8));
        tm *= 0.125f;
        float mold = mrow[fr][r];
        float mnew = fmaxf(mold, tm);
        float alpha = __expf(mold - mnew);
        mrow[fr][r] = mnew;
        float ps = 0.f;
#pragma unroll
        for (int fc = 0; fc < 8; ++fc) {
          float pv = __expf(sacc[fr][fc][r] * 0.125f - mnew);
          sacc[fr][fc][r] = pv;
          ps += pv;
        }
        ps += __shfl_xor(ps, 1);
        ps += __shfl_xor(ps, 2);
        ps += __shfl_xor(ps, 4);
        ps += __shfl_xor(ps, 8);
        lrow[fr][r] = lrow[fr][r] * alpha + ps;
#pragma unroll
        for (int nf = 0; nf < 4; ++nf) oacc[fr][nf][r] *= alpha;
      }
    }

    // write P (bf16) to per-wave LDS, swizzled
#pragma unroll
    for (int fr = 0; fr < 2; ++fr)
#pragma unroll
      for (int fc = 0; fc < 8; ++fc)
#pragma unroll
        for (int r = 0; r < 4; ++r) {
          int row = fr * 16 + g * 4 + r;
          int col = fc * 16 + i16;
          int ch = (col >> 3) ^ (row & 15);
          Pw[row * 128 + ch * 8 + (col & 7)] = f2bf(sacc[fr][fc][r]);
        }

    // O += P @ V
#pragma unroll
    for (int kc = 0; kc < 4; ++kc) {
      vshort8 pa[2], vb[4];
#pragma unroll
      for (int fr = 0; fr < 2; ++fr) {
        int row = fr * 16 + i16;
        int ch = (4 * kc + g) ^ (row & 15);
        pa[fr] = *(const vshort8*)&Pw[row * 128 + ch * 8];
      }
#pragma unroll
      for (int nf = 0; nf < 4; ++nf) {
        int row = nf * 16 + i16;
        int ch = (4 * kc + g) ^ (row & 15);
        vb[nf] = *(const vshort8*)&Vs[row * 128 + ch * 8];
      }
#pragma unroll
      for (int fr = 0; fr < 2; ++fr)
#pragma unroll
        for (int nf = 0; nf < 4; ++nf)
          oacc[fr][nf] = mfma_bf16(pa[fr], vb[nf], oacc[fr][nf]);
    }
  }

  // normalize + store
#pragma unroll
  for (int fr = 0; fr < 2; ++fr) {
    float inv[4];
#pragma unroll
    for (int r = 0; r < 4; ++r) inv[r] = 1.0f / lrow[fr][r];
#pragma unroll
    for (int nf = 0; nf < 4; ++nf)
#pragma unroll
      for (int r = 0; r < 4; ++r) {
        int qrow = qb * 128 + wid * 32 + fr * 16 + g * 4 + r;
        int col = h * 64 + nf * 16 + i16;
        O[(size_t)(b * 2048 + qrow) * 1024 + col] = f2bf(oacc[fr][nf][r] * inv[r]);
      }
  }
}

extern "C" void kernel_launch(void* const* d_in, const int* in_sizes, int n_in,
                              void* d_out, int out_size, void* d_ws, size_t ws_size,
                              hipStream_t stream) {
  const float* q  = (const float*)d_in[0];
  const float* k  = (const float*)d_in[1];
  const float* v  = (const float*)d_in[2];
  const float* wq = (const float*)d_in[3];
  const float* wk = (const float*)d_in[4];
  const float* wv = (const float*)d_in[5];
  const float* wo = (const float*)d_in[6];
  float* out = (float*)d_out;

  const int M = 8192, D = 1024;
  // Q,K (bf16) live in d_out (32MB = exactly 2x16MB); dead before final GEMM writes out.
  u16* Qb = (u16*)d_out;
  u16* Kb = Qb + (size_t)M * D;
  // workspace: xb (reused conv buffer, later attn output) | Vb | Vtg | 4 weights
  u16* xb  = (u16*)d_ws;
  u16* Vb  = xb + (size_t)M * D;
  u16* Vtg = Vb + (size_t)M * D;
  u16* wqt = Vtg + (size_t)M * D;
  u16* wkt = wqt + (size_t)D * D;
  u16* wvt = wkt + (size_t)D * D;
  u16* wot = wvt + (size_t)D * D;

  dim3 blk(256);
  dim3 gw(16, 16);
  wtrans<<<gw, blk, 0, stream>>>(wq, wqt);
  wtrans<<<gw, blk, 0, stream>>>(wk, wkt);
  wtrans<<<gw, blk, 0, stream>>>(wv, wvt);
  wtrans<<<gw, blk, 0, stream>>>(wo, wot);

  int n4 = M * D / 4;
  dim3 ggemm(8, 64);
  cvtk<<<2048, blk, 0, stream>>>(q, xb, n4);
  gemm_nt<0><<<ggemm, blk, 0, stream>>>(xb, wqt, nullptr, Qb, M, D, D);
  cvtk<<<2048, blk, 0, stream>>>(k, xb, n4);
  gemm_nt<0><<<ggemm, blk, 0, stream>>>(xb, wkt, nullptr, Kb, M, D, D);
  cvtk<<<2048, blk, 0, stream>>>(v, xb, n4);
  gemm_nt<0><<<ggemm, blk, 0, stream>>>(xb, wvt, nullptr, Vb, M, D, D);

  vtrans<<<dim3(32, 64), blk, 0, stream>>>(Vb, Vtg);
  attn_fwd<<<dim3(16, 64), blk, 0, stream>>>(Qb, Kb, Vtg, xb /* -> AO */);
  gemm_nt<1><<<ggemm, blk, 0, stream>>>(xb, wot, out, nullptr, M, D, D);
}

// Round 2
// 311.157 us; speedup vs baseline: 1.2864x; 1.2864x over previous
//
#include <hip/hip_runtime.h>

typedef unsigned short u16;
typedef short vshort8 __attribute__((ext_vector_type(8)));
typedef __bf16 vbf16x8 __attribute__((ext_vector_type(8)));
typedef float vf32x4 __attribute__((ext_vector_type(4)));
typedef float vf32x16 __attribute__((ext_vector_type(16)));

__device__ __forceinline__ u16 f2bf(float f) {
  unsigned u = __builtin_bit_cast(unsigned, f);
  u += 0x7FFFu + ((u >> 16) & 1u);
  return (u16)(u >> 16);
}

__device__ __forceinline__ unsigned cvtpk(float lo, float hi) {
  unsigned r;
  asm("v_cvt_pk_bf16_f32 %0, %1, %2" : "=v"(r) : "v"(lo), "v"(hi));
  return r;
}

__device__ __forceinline__ vf32x4 mfma_bf16(vshort8 a, vshort8 b, vf32x4 c) {
  return __builtin_amdgcn_mfma_f32_16x16x32_bf16(
      __builtin_bit_cast(vbf16x8, a), __builtin_bit_cast(vbf16x8, b), c, 0, 0, 0);
}

__device__ __forceinline__ vf32x16 mfma32(vshort8 a, vshort8 b, vf32x16 c) {
  return __builtin_amdgcn_mfma_f32_32x32x16_bf16(
      __builtin_bit_cast(vbf16x8, a), __builtin_bit_cast(vbf16x8, b), c, 0, 0, 0);
}

__device__ __forceinline__ void gload16(const void* g, void* l) {
  __builtin_amdgcn_global_load_lds(
      (const __attribute__((address_space(1))) void*)g,
      (__attribute__((address_space(3))) void*)l, 16, 0, 0);
}

// ---------------- fp32 -> bf16 elementwise ----------------
__global__ __launch_bounds__(256) void cvtk(const float* __restrict__ in,
                                            u16* __restrict__ out, int n4) {
  int idx = blockIdx.x * 256 + threadIdx.x;
  int stride = gridDim.x * 256;
  for (int i = idx; i < n4; i += stride) {
    float4 v = ((const float4*)in)[i];
    unsigned lo = (unsigned)f2bf(v.x) | ((unsigned)f2bf(v.y) << 16);
    unsigned hi = (unsigned)f2bf(v.z) | ((unsigned)f2bf(v.w) << 16);
    uint2 o; o.x = lo; o.y = hi;
    *(uint2*)&out[(size_t)i * 4] = o;
  }
}

// ---------------- weight transpose + cvt: W[k][n] f32 -> Wt[n][k] bf16 ----------------
__global__ __launch_bounds__(256) void wtrans(const float* __restrict__ W,
                                              u16* __restrict__ Wt) {
  __shared__ u16 tile[64][72];
  int t = threadIdx.x;
  int n0 = blockIdx.x * 64, k0 = blockIdx.y * 64;
#pragma unroll
  for (int it = 0; it < 4; ++it) {
    int cid = it * 256 + t;
    int r = cid >> 4, c4 = cid & 15;
    float4 v = *(const float4*)&W[(k0 + r) * 1024 + n0 + c4 * 4];
    u16* d = &tile[r][c4 * 4];
    d[0] = f2bf(v.x); d[1] = f2bf(v.y); d[2] = f2bf(v.z); d[3] = f2bf(v.w);
  }
  __syncthreads();
#pragma unroll
  for (int it = 0; it < 4; ++it) {
    int cid = it * 256 + t;
    int rn = cid >> 4, c4 = cid & 15;
    unsigned lo = (unsigned)tile[c4 * 4 + 0][rn] | ((unsigned)tile[c4 * 4 + 1][rn] << 16);
    unsigned hi = (unsigned)tile[c4 * 4 + 2][rn] | ((unsigned)tile[c4 * 4 + 3][rn] << 16);
    uint2 o; o.x = lo; o.y = hi;
    *(uint2*)&Wt[(n0 + rn) * 1024 + k0 + c4 * 4] = o;
  }
}

// ---------------- V transpose: V[b*2048+s][h*64+d] -> Vt[(bh*64+d)][s] (bf16) ----------------
__global__ __launch_bounds__(256) void vtrans(const u16* __restrict__ V,
                                              u16* __restrict__ Vt) {
  __shared__ u16 tile[64][72];
  int t = threadIdx.x;
  int s0 = blockIdx.x * 64;
  int bh = blockIdx.y, b = bh >> 4, h = bh & 15;
#pragma unroll
  for (int it = 0; it < 2; ++it) {
    int cid = it * 256 + t;
    int r = cid >> 3, c8 = cid & 7;
    vshort8 v = *(const vshort8*)&V[(size_t)(b * 2048 + s0 + r) * 1024 + h * 64 + c8 * 8];
    *(vshort8*)&tile[r][c8 * 8] = v;
  }
  __syncthreads();
#pragma unroll
  for (int it = 0; it < 2; ++it) {
    int cid = it * 256 + t;
    int rd = cid >> 3, c8 = cid & 7;
    unsigned w[4];
#pragma unroll
    for (int j = 0; j < 4; ++j) {
      unsigned lo = tile[c8 * 8 + 2 * j][rd];
      unsigned hi = tile[c8 * 8 + 2 * j + 1][rd];
      w[j] = lo | (hi << 16);
    }
    uint4 o; o.x = w[0]; o.y = w[1]; o.z = w[2]; o.w = w[3];
    *(uint4*)&Vt[(size_t)(bh * 64 + rd) * 2048 + s0 + c8 * 8] = o;
  }
}

// ---------------- bf16 GEMM: C[M,N] = (A[M,K] * Bt[N,K]^T) * oscale ----------------
template <int OUTF32>
__global__ __launch_bounds__(256) void gemm_nt(const u16* __restrict__ A,
                                               const u16* __restrict__ Bt,
                                               float* __restrict__ Cf,
                                               u16* __restrict__ Cb,
                                               int M, int N, int K, float oscale) {
  __shared__ __align__(16) u16 As[128 * 64];
  __shared__ __align__(16) u16 Bs[128 * 64];
  int t = threadIdx.x, lane = t & 63, wid = t >> 6;
  int g = lane >> 4, i16 = lane & 15;
  int n0 = blockIdx.x * 128, m0 = blockIdx.y * 128;
  int wm = wid >> 1, wn = wid & 1;

  vf32x4 acc[4][4];
#pragma unroll
  for (int a = 0; a < 4; ++a)
#pragma unroll
    for (int b = 0; b < 4; ++b) acc[a][b] = (vf32x4){0.f, 0.f, 0.f, 0.f};

  int ldsbase = (wid * 64) * 8;
  for (int kt = 0; kt < K / 64; ++kt) {
    if (kt) __syncthreads();
#pragma unroll
    for (int it = 0; it < 4; ++it) {
      int cid = it * 256 + t;
      int row = cid >> 3, c = cid & 7, sc = c ^ (row & 7);
      gload16(A + (size_t)(m0 + row) * K + kt * 64 + sc * 8, &As[it * 2048 + ldsbase]);
    }
#pragma unroll
    for (int it = 0; it < 4; ++it) {
      int cid = it * 256 + t;
      int row = cid >> 3, c = cid & 7, sc = c ^ (row & 7);
      gload16(Bt + (size_t)(n0 + row) * K + kt * 64 + sc * 8, &Bs[it * 2048 + ldsbase]);
    }
    __syncthreads();
#pragma unroll
    for (int kc = 0; kc < 2; ++kc) {
      vshort8 af[4], bf[4];
#pragma unroll
      for (int mf = 0; mf < 4; ++mf) {
        int row = wm * 64 + mf * 16 + i16;
        int ch = (kc * 4 + g) ^ (row & 7);
        af[mf] = *(const vshort8*)&As[row * 64 + ch * 8];
      }
#pragma unroll
      for (int nf = 0; nf < 4; ++nf) {
        int row = wn * 64 + nf * 16 + i16;
        int ch = (kc * 4 + g) ^ (row & 7);
        bf[nf] = *(const vshort8*)&Bs[row * 64 + ch * 8];
      }
#pragma unroll
      for (int mf = 0; mf < 4; ++mf)
#pragma unroll
        for (int nf = 0; nf < 4; ++nf)
          acc[mf][nf] = mfma_bf16(af[mf], bf[nf], acc[mf][nf]);
    }
  }
#pragma unroll
  for (int mf = 0; mf < 4; ++mf)
#pragma unroll
    for (int nf = 0; nf < 4; ++nf)
#pragma unroll
      for (int r = 0; r < 4; ++r) {
        int m = m0 + wm * 64 + mf * 16 + g * 4 + r;
        int n = n0 + wn * 64 + nf * 16 + i16;
        if (OUTF32)
          Cf[(size_t)m * N + n] = acc[mf][nf][r] * oscale;
        else
          Cb[(size_t)m * N + n] = f2bf(acc[mf][nf][r] * oscale);
      }
}

// ---------------- fused flash attention, zero-LDS per-wave, 32x32 MFMA ----------------
// Q (pre-scaled by 0.125*log2e), K: [8192,1024] bf16; Vt: [64*64,2048] bf16; O: [8192,1024] bf16
// Swapped operands: S^T = mfma(K,Q) -> lane owns q=lane&31; O^T = mfma(Vt,P) keeps q lane-local.
__global__ __launch_bounds__(512, 2) void attn_fwd2(const u16* __restrict__ Q,
                                                    const u16* __restrict__ K,
                                                    const u16* __restrict__ Vt,
                                                    u16* __restrict__ O) {
  int t = threadIdx.x, lane = t & 63, w = t >> 6;
  int l31 = lane & 31, hi = lane >> 5;
  int i = blockIdx.x;
  int qb = (i >> 3) & 3;                 // 4 q-chunks of 512 rows
  int bh = (i & 7) + 8 * (i >> 5);       // same-bh blocks share XCD (i%8)
  int b = bh >> 4, h = bh & 15;

  const u16* Qbase = Q + (size_t)(b * 2048 + qb * 512 + w * 64) * 1024 + h * 64;
  const u16* Kbase = K + (size_t)(b * 2048) * 1024 + h * 64;
  const u16* Vbase = Vt + (size_t)(bh * 64) * 2048;

  // Q fragments: B-operand, q = fq*32 + l31, d = dc*16 + hi*8 + j
  vshort8 qf[2][4];
#pragma unroll
  for (int fq = 0; fq < 2; ++fq)
#pragma unroll
    for (int dc = 0; dc < 4; ++dc)
      qf[fq][dc] = *(const vshort8*)&Qbase[(size_t)(fq * 32 + l31) * 1024 + dc * 16 + hi * 8];

  vf32x16 oacc[2][2];  // [dm][fq], O^T: row d=crow(r,hi)+32dm, col q=l31+32fq
#pragma unroll
  for (int dm = 0; dm < 2; ++dm)
#pragma unroll
    for (int fq = 0; fq < 2; ++fq)
#pragma unroll
      for (int r = 0; r < 16; ++r) oacc[dm][fq][r] = 0.f;
  float mrun[2] = {-3.0e38f, -3.0e38f}, lrun[2] = {0.f, 0.f};

  for (int kt = 0; kt < 32; ++kt) {
    __syncthreads();  // convoy alignment: 8 waves share K/V tiles via L1
    vshort8 kf[2][4], vtf[2][4];
#pragma unroll
    for (int ks = 0; ks < 2; ++ks)
#pragma unroll
      for (int dc = 0; dc < 4; ++dc)
        kf[ks][dc] = *(const vshort8*)&Kbase[(size_t)(kt * 64 + ks * 32 + l31) * 1024 + dc * 16 + hi * 8];
#pragma unroll
    for (int dm = 0; dm < 2; ++dm)
#pragma unroll
      for (int s = 0; s < 4; ++s)
        vtf[dm][s] = *(const vshort8*)&Vbase[(size_t)(dm * 32 + l31) * 2048 + kt * 64 + s * 16 + hi * 8];

    // S^T tiles: sacc[ks][fq], row k = ks*32+crow(r,hi), col q = l31 (+32fq)
    vf32x16 sacc[2][2];
#pragma unroll
    for (int ks = 0; ks < 2; ++ks)
#pragma unroll
      for (int fq = 0; fq < 2; ++fq)
#pragma unroll
        for (int r = 0; r < 16; ++r) sacc[ks][fq][r] = 0.f;

    __builtin_amdgcn_s_setprio(1);
#pragma unroll
    for (int dc = 0; dc < 4; ++dc)
#pragma unroll
      for (int ks = 0; ks < 2; ++ks)
#pragma unroll
        for (int fq = 0; fq < 2; ++fq)
          sacc[ks][fq] = mfma32(kf[ks][dc], qf[fq][dc], sacc[ks][fq]);
    __builtin_amdgcn_s_setprio(0);

    // online softmax in exp2 domain (scale folded into Q)
#pragma unroll
    for (int fq = 0; fq < 2; ++fq) {
      float pmax = sacc[0][fq][0];
#pragma unroll
      for (int ks = 0; ks < 2; ++ks)
#pragma unroll
        for (int r = 0; r < 16; ++r) pmax = fmaxf(pmax, sacc[ks][fq][r]);
      pmax = fmaxf(pmax, __shfl_xor(pmax, 32));
      float mold = mrun[fq];
      if (pmax > mold + 8.f) {  // defer-max: skip rescale when growth small
        float al = exp2f(mold - pmax);
        lrun[fq] *= al;
#pragma unroll
        for (int dm = 0; dm < 2; ++dm)
#pragma unroll
          for (int r = 0; r < 16; ++r) oacc[dm][fq][r] *= al;
        mrun[fq] = pmax;
      }
      float mm = mrun[fq];
      float ssum = 0.f;
#pragma unroll
      for (int ks = 0; ks < 2; ++ks)
#pragma unroll
        for (int r = 0; r < 16; ++r) {
          float p = exp2f(sacc[ks][fq][r] - mm);
          sacc[ks][fq][r] = p;
          ssum += p;
        }
      ssum += __shfl_xor(ssum, 32);
      lrun[fq] += ssum;
    }

    // P redistribution (in-register) + PV
#pragma unroll
    for (int s = 0; s < 4; ++s) {
      vshort8 pb[2];
#pragma unroll
      for (int fq = 0; fq < 2; ++fq) {
        const int ks = s >> 1, s1 = s & 1;
        float a0 = sacc[ks][fq][8 * s1 + 0], a1 = sacc[ks][fq][8 * s1 + 1];
        float a2 = sacc[ks][fq][8 * s1 + 2], a3 = sacc[ks][fq][8 * s1 + 3];
        float b0 = sacc[ks][fq][8 * s1 + 4], b1 = sacc[ks][fq][8 * s1 + 5];
        float b2 = sacc[ks][fq][8 * s1 + 6], b3 = sacc[ks][fq][8 * s1 + 7];
        unsigned wA0 = cvtpk(a0, a1), wA1 = cvtpk(a2, a3);
        unsigned wB0 = cvtpk(b0, b1), wB1 = cvtpk(b2, b3);
        unsigned sA0 = hi ? wB0 : wA0, sA1 = hi ? wB1 : wA1;   // self half (u2=hi)
        unsigned sd0 = hi ? wA0 : wB0, sd1 = hi ? wA1 : wB1;   // partner's half (u2=1-hi)
        unsigned rv0 = __shfl_xor((int)sd0, 32), rv1 = __shfl_xor((int)sd1, 32);
        uint4 wv;
        wv.x = hi ? rv0 : sA0; wv.y = hi ? rv1 : sA1;
        wv.z = hi ? sA0 : rv0; wv.w = hi ? sA1 : rv1;
        pb[fq] = __builtin_bit_cast(vshort8, wv);
      }
      __builtin_amdgcn_s_setprio(1);
#pragma unroll
      for (int dm = 0; dm < 2; ++dm)
#pragma unroll
        for (int fq = 0; fq < 2; ++fq)
          oacc[dm][fq] = mfma32(vtf[dm][s], pb[fq], oacc[dm][fq]);
      __builtin_amdgcn_s_setprio(0);
    }
  }

  // epilogue: O[q][d], d = 8u+4hi+t (+32dm), q = lane-local
#pragma unroll
  for (int fq = 0; fq < 2; ++fq) {
    float inv = 1.f / lrun[fq];
    size_t qrow = (size_t)(b * 2048 + qb * 512 + w * 64 + fq * 32 + l31);
#pragma unroll
    for (int dm = 0; dm < 2; ++dm)
#pragma unroll
      for (int u = 0; u < 4; ++u) {
        unsigned w0 = cvtpk(oacc[dm][fq][4 * u + 0] * inv, oacc[dm][fq][4 * u + 1] * inv);
        unsigned w1 = cvtpk(oacc[dm][fq][4 * u + 2] * inv, oacc[dm][fq][4 * u + 3] * inv);
        uint2 o; o.x = w0; o.y = w1;
        *(uint2*)&O[qrow * 1024 + h * 64 + dm * 32 + 8 * u + 4 * hi] = o;
      }
  }
}

extern "C" void kernel_launch(void* const* d_in, const int* in_sizes, int n_in,
                              void* d_out, int out_size, void* d_ws, size_t ws_size,
                              hipStream_t stream) {
  const float* q  = (const float*)d_in[0];
  const float* k  = (const float*)d_in[1];
  const float* v  = (const float*)d_in[2];
  const float* wq = (const float*)d_in[3];
  const float* wk = (const float*)d_in[4];
  const float* wv = (const float*)d_in[5];
  const float* wo = (const float*)d_in[6];
  float* out = (float*)d_out;

  const int M = 8192, D = 1024;
  u16* Qb = (u16*)d_out;                // Q,K (bf16) parked in d_out
  u16* Kb = Qb + (size_t)M * D;
  u16* xb  = (u16*)d_ws;
  u16* Vb  = xb + (size_t)M * D;
  u16* Vtg = Vb + (size_t)M * D;
  u16* wqt = Vtg + (size_t)M * D;
  u16* wkt = wqt + (size_t)D * D;
  u16* wvt = wkt + (size_t)D * D;
  u16* wot = wvt + (size_t)D * D;

  dim3 blk(256);
  dim3 gw(16, 16);
  wtrans<<<gw, blk, 0, stream>>>(wq, wqt);
  wtrans<<<gw, blk, 0, stream>>>(wk, wkt);
  wtrans<<<gw, blk, 0, stream>>>(wv, wvt);
  wtrans<<<gw, blk, 0, stream>>>(wo, wot);

  const float QSCALE = 0.125f * 1.44269504088896f;  // 1/sqrt(64) * log2(e)
  int n4 = M * D / 4;
  dim3 ggemm(8, 64);
  cvtk<<<2048, blk, 0, stream>>>(q, xb, n4);
  gemm_nt<0><<<ggemm, blk, 0, stream>>>(xb, wqt, nullptr, Qb, M, D, D, QSCALE);
  cvtk<<<2048, blk, 0, stream>>>(k, xb, n4);
  gemm_nt<0><<<ggemm, blk, 0, stream>>>(xb, wkt, nullptr, Kb, M, D, D, 1.0f);
  cvtk<<<2048, blk, 0, stream>>>(v, xb, n4);
  gemm_nt<0><<<ggemm, blk, 0, stream>>>(xb, wvt, nullptr, Vb, M, D, D, 1.0f);

  vtrans<<<dim3(32, 64), blk, 0, stream>>>(Vb, Vtg);
  attn_fwd2<<<dim3(256), dim3(512), 0, stream>>>(Qb, Kb, Vtg, xb /* -> attn out */);
  gemm_nt<1><<<ggemm, blk, 0, stream>>>(xb, wot, out, nullptr, M, D, D, 1.0f);
}